// Round 10
// baseline (204.025 us; speedup 1.0000x reference)
//
#include <hip/hip_runtime.h>

#define TM 128
#define TN 128

typedef float f32x4 __attribute__((ext_vector_type(4)));
typedef int   i32x4 __attribute__((ext_vector_type(4)));
typedef int   i32x8 __attribute__((ext_vector_type(8)));

// E8M0 scales: value = 2^(byte-127). A-scale = 2^0; B holds cent*2^6, B-scale = 2^-6.
#define SCALE_A 127
#define SCALE_B 121

// Fragment-tiled operand layout (R13): buf[slab t][group g][slot s][row r] of
// 16-B chunks, where group = row/16, slab = k/128, slot = (k/16)&7. A wave's
// MFMA fragment load is then: lane (quad q, l16) reads slots 2q,2q+1 of row
// l16 -> two dwordx4 at voff = q*512 + l16*16 (+256), wave-uniform base.
// Strides: slot 256 B, group 2048 B, slab = ngroups*2048.

// ---- prep_both: fused prep_w (blocks [0,1024)) + prep_x (blocks [1024,9216)).
__global__ __launch_bounds__(256) void prep_both(const float* __restrict__ W,
                                                 unsigned char* __restrict__ c8,
                                                 float* __restrict__ s,
                                                 const float* __restrict__ x,
                                                 unsigned int* __restrict__ x8,
                                                 float* __restrict__ x2) {
    __shared__ float tile[64][65];
    __shared__ float cred[4][64];
    const int tid = threadIdx.x;

    if (blockIdx.x < 1024) {            // ---- prep_w body ----
        const int tx = tid & 63;
        const int ty = tid >> 6;
        const int q0 = (blockIdx.x & 15) * 64;
        const int e0 = (blockIdx.x >> 4) * 64;   // e = r*1024 + d
        const int r  = e0 >> 10;
        const int d0 = e0 & 1023;

        float csum = 0.f;
        #pragma unroll
        for (int p = 0; p < 16; p++) {
            const int er = p * 4 + ty;
            const float v = W[(size_t)(e0 + er) * 1024 + q0 + tx];
            tile[er][tx] = v;
            csum += v * v;
        }
        cred[ty][tx] = csum;
        __syncthreads();
        if (ty == 0) {
            atomicAdd(&s[4 * (q0 + tx) + r],
                      cred[0][tx] + cred[1][tx] + cred[2][tx] + cred[3][tx]);
        }
        // c8 fragment-tiled write: c = 4*(q0+qq)+r (row), d = d0+dg*4 (col);
        // h = c>>4 = q>>2, rowInGroup = (q&3)*4+r, slab = d>>7, slot = (d>>4)&7.
        #pragma unroll
        for (int p = 0; p < 4; p++) {
            const int qq = p * 16 + (tid >> 4);
            const int dg = tid & 15;
            const int q  = q0 + qq;
            const int d  = d0 + dg * 4;
            const float v0 = tile[dg * 4 + 0][qq] * 64.f;
            const float v1 = tile[dg * 4 + 1][qq] * 64.f;
            const float v2 = tile[dg * 4 + 2][qq] * 64.f;
            const float v3 = tile[dg * 4 + 3][qq] * 64.f;
            int pk = __builtin_amdgcn_cvt_pk_fp8_f32(v0, v1, 0, false);
            pk = __builtin_amdgcn_cvt_pk_fp8_f32(v2, v3, pk, true);
            const size_t off = ((size_t)((d >> 7) * 256 + (q >> 2)) * 8 + ((d >> 4) & 7)) * 256
                               + ((q & 3) * 4 + r) * 16 + (dg & 3) * 4;
            *(unsigned int*)(c8 + off) = (unsigned int)pk;
        }
    } else {                            // ---- prep_x body ----
        const int b = blockIdx.x - 1024;
        const float4 v = ((const float4*)(x + (size_t)b * 1024))[tid];
        float sum = v.x * v.x + v.y * v.y + v.z * v.z + v.w * v.w;
        int p = __builtin_amdgcn_cvt_pk_fp8_f32(v.x, v.y, 0, false);
        p = __builtin_amdgcn_cvt_pk_fp8_f32(v.z, v.w, p, true);
        // fragment-tiled: k = 4*tid -> slab = tid>>5, slot = (tid>>2)&7,
        // byte = (tid&3)*4; g = b>>4, row = b&15.
        const size_t off = ((size_t)((tid >> 5) * 512 + (b >> 4)) * 8 + ((tid >> 2) & 7)) * 256
                           + (b & 15) * 16 + (tid & 3) * 4;
        *(unsigned int*)((unsigned char*)x8 + off) = (unsigned int)p;
        #pragma unroll
        for (int o = 32; o > 0; o >>= 1) sum += __shfl_down(sum, o, 64);
        if ((tid & 63) == 0) cred[0][tid >> 6] = sum;
        __syncthreads();
        if (tid == 0) x2[b] = cred[0][0] + cred[0][1] + cred[0][2] + cred[0][3];
    }
}

// ---- gemm_bt: out[m][n] = 2*sum_k A[m][k]*Bt[n][k] - x2[m] - s[n] - bias[n] ----
// R13: BARRIER-FREE K-loop. Operands are fragment-tiled in workspace (see
// prep), so each wave loads af/bf straight from global (L2-hot: A-stripe 1 MB
// + hot B resident per XCD; duplicate wave-pair reads hit L1) into registers.
// No LDS staging, no ds_read, no s_barrier in the main loop -> the per-slab
// phase serialization (R12's additive ~54 us) dissolves; waves overlap loads
// and MFMA freely. 2-deep register double-buffer, counted vmcnt(16).
// LDS (64 KB) only used by the proven epilogue transpose.
__global__ __launch_bounds__(256, 2) void gemm_bt(const unsigned char* __restrict__ A,
                                                  const unsigned char* __restrict__ Bt,
                                                  const float* __restrict__ x2,
                                                  const float* __restrict__ s,
                                                  const float* __restrict__ bias,
                                                  float* __restrict__ out,
                                                  int M, int N, int K) {
    __shared__ float ftile[128 * 128];   // 64 KB, epilogue only

    const int tid  = threadIdx.x;
    const int wave = tid >> 6;
    const int lane = tid & 63;
    const int quad = lane >> 4;
    const int l16  = lane & 15;
    const int wm   = wave & 1;     // m half: 64 rows
    const int wn   = wave >> 1;    // n half: 64 cols

    // XCD m-stripe swizzle (m-tiles = 64, n-tiles = 32)
    const int flat = blockIdx.x;    // 2048 blocks
    const int xcd  = flat & 7;
    const int idx  = flat >> 3;     // 0..255
    const int mt   = (idx & 7) | (xcd << 3);   // 8 m-tiles per XCD -> 1 MB A-stripe in its L2
    const int nt   = idx >> 3;      // 0..31
    const int tile_m = mt * TM;
    const int tile_n = nt * TN;

    // fragment addressing: wave-uniform group bases + per-lane voff
    const int g0 = (tile_m >> 4) + wm * 4;     // A groups g0..g0+3 (512 groups total)
    const int h0 = (tile_n >> 4) + wn * 4;     // B groups h0..h0+3 (256 groups total)
    const int voff = quad * 512 + l16 * 16;
    const unsigned char* paw = A  + (size_t)g0 * 2048 + voff;   // A slab stride 1 MB
    const unsigned char* pbw = Bt + (size_t)h0 * 2048 + voff;   // B slab stride 512 KB

    f32x4 acc[4][4];
    #pragma unroll
    for (int i = 0; i < 4; i++)
        #pragma unroll
        for (int j = 0; j < 4; j++) acc[i][j] = (f32x4){0.f, 0.f, 0.f, 0.f};

#define LOADF(Abuf, Bbuf, T) do {                                              \
    const unsigned char* pa_ = paw + ((size_t)(T) << 20);                      \
    const unsigned char* pb_ = pbw + ((size_t)(T) * 524288);                   \
    _Pragma("unroll")                                                          \
    for (int i_ = 0; i_ < 4; i_++) {                                           \
        Abuf[2 * i_]     = *(const i32x4*)(pa_ + i_ * 2048);                   \
        Abuf[2 * i_ + 1] = *(const i32x4*)(pa_ + i_ * 2048 + 256);             \
    }                                                                          \
    _Pragma("unroll")                                                          \
    for (int j_ = 0; j_ < 4; j_++) {                                           \
        Bbuf[2 * j_]     = *(const i32x4*)(pb_ + j_ * 2048);                   \
        Bbuf[2 * j_ + 1] = *(const i32x4*)(pb_ + j_ * 2048 + 256);             \
    }                                                                          \
} while (0)

#define COMP(Abuf, Bbuf) do {                                                  \
    i32x8 af_[4], bf_[4];                                                      \
    _Pragma("unroll")                                                          \
    for (int i_ = 0; i_ < 4; i_++)                                             \
        af_[i_] = __builtin_shufflevector(Abuf[2 * i_], Abuf[2 * i_ + 1],      \
                                          0, 1, 2, 3, 4, 5, 6, 7);             \
    _Pragma("unroll")                                                          \
    for (int j_ = 0; j_ < 4; j_++)                                             \
        bf_[j_] = __builtin_shufflevector(Bbuf[2 * j_], Bbuf[2 * j_ + 1],      \
                                          0, 1, 2, 3, 4, 5, 6, 7);             \
    __builtin_amdgcn_s_setprio(1);                                             \
    _Pragma("unroll")                                                          \
    for (int j_ = 0; j_ < 4; j_++)                                             \
        _Pragma("unroll")                                                      \
        for (int i_ = 0; i_ < 4; i_++)                                         \
            acc[i_][j_] = __builtin_amdgcn_mfma_scale_f32_16x16x128_f8f6f4(    \
                bf_[j_], af_[i_], acc[i_][j_], 0, 0, 0, SCALE_B, 0, SCALE_A);  \
    __builtin_amdgcn_s_setprio(0);                                             \
} while (0)

    i32x4 A0[8], B0[8], A1[8], B1[8];
    LOADF(A0, B0, 0);
    LOADF(A1, B1, 1);
    #pragma unroll
    for (int t = 0; t < 8; t += 2) {
        // queue: [16 slab-t][16 slab-(t+1)] -> vmcnt(16) retires slab t
        asm volatile("s_waitcnt vmcnt(16)" ::: "memory");
        COMP(A0, B0);
        if (t + 2 < 8) {
            LOADF(A0, B0, t + 2);
            asm volatile("s_waitcnt vmcnt(16)" ::: "memory");   // slab t+1 ready
        } else {
            asm volatile("s_waitcnt vmcnt(0)" ::: "memory");    // last slab ready
        }
        COMP(A1, B1);
        if (t + 3 < 8) LOADF(A1, B1, t + 3);
    }
#undef LOADF
#undef COMP

    // ---- epilogue: finish math in regs, swizzled LDS transpose, coalesced stores ----
    // fragment (transposed): m_local = wm*64 + i*16 + l16, n_local = wn*64 + j*16 + quad*4+rr
    // ftile flat [128][128] f32; chunk cn = n_local>>2; swizzle cn ^= (m_local&7)<<2.
    float xm[4];
    #pragma unroll
    for (int i = 0; i < 4; i++)
        xm[i] = x2[tile_m + wm * 64 + i * 16 + l16];
    #pragma unroll
    for (int j = 0; j < 4; j++) {
        const int n0 = tile_n + wn * 64 + j * 16 + quad * 4;
        const f32x4 sv = *(const f32x4*)(s + n0);
        const f32x4 bv = *(const f32x4*)(bias + n0);
        #pragma unroll
        for (int i = 0; i < 4; i++) {
            f32x4 v;
            #pragma unroll
            for (int rr = 0; rr < 4; rr++)
                v[rr] = 2.f * acc[i][j][rr] - xm[i] - sv[rr] - bv[rr];
            const int ml = wm * 64 + i * 16 + l16;
            const int cn = wn * 16 + j * 4 + quad;
            *(f32x4*)(ftile + ml * 128 + ((cn ^ ((ml & 7) << 2)) << 2)) = v;
        }
    }
    __syncthreads();
    // read back row-major: wave covers 2 rows x 512 B contiguous per instruction.
    // NORMAL stores: land in L2, drain to HBM async under other blocks' K-loops.
    #pragma unroll
    for (int it = 0; it < 16; ++it) {
        const int r = it * 8 + (tid >> 5);   // 0..127
        const int c = tid & 31;              // f32x4 chunk within row
        const f32x4 v = *(const f32x4*)(ftile + r * 128 + ((c ^ ((r & 7) << 2)) << 2));
        *(f32x4*)(out + (size_t)(tile_m + r) * N + tile_n + c * 4) = v;
    }
}

extern "C" void kernel_launch(void* const* d_in, const int* in_sizes, int n_in,
                              void* d_out, int out_size, void* d_ws, size_t ws_size,
                              hipStream_t stream) {
    const float* x    = (const float*)d_in[0];
    const float* w    = (const float*)d_in[1];
    const float* bias = (const float*)d_in[2];
    float* out = (float*)d_out;

    const int C = in_sizes[2];              // 4096
    const int D = in_sizes[1] / C;          // 1024
    const int B = in_sizes[0] / D;          // 8192

    unsigned char* x8 = (unsigned char*)d_ws;              // B*D fp8 = 8 MB (fragment-tiled)
    unsigned char* c8 = x8 + (size_t)B * D;                // C*D fp8 = 4 MB (fragment-tiled)
    float* x2 = (float*)(c8 + (size_t)C * D);              // B fp32
    float* s  = x2 + B;                                    // C fp32

    hipMemsetAsync(s, 0, (size_t)C * sizeof(float), stream);   // s = 0; bias folded into gemm epilogue
    prep_both<<<1024 + B, 256, 0, stream>>>(w, c8, s, x, (unsigned int*)x8, x2);
    const int nblocks = (B / TM) * (C / TN);
    gemm_bt<<<nblocks, 256, 0, stream>>>(x8, c8, x2, s, bias, out, B, C, D);
}